// Round 18
// baseline (205.720 us; speedup 1.0000x reference)
//
#include <hip/hip_runtime.h>
#include <hip/hip_fp8.h>

// LinearCrossAttentionAdd on MI355X (gfx950)
// Pipeline:
//  k01: [x<4] x (b,c,n) f32 -> xt (b,n,c) bf16 ; [x==4] w->bf16, lk/lq dots
//  k2: GEMM1 per batch BM=256 (512 thr): A(W) in REGISTERS (L2-resident),
//      B via gload_lds. Epilogues: q softmax -> qh bf16; k/v -> fp8 + ksum
//  k3: ctx partials (fp8 MFMA)
//  k4: M = scale/ksum * (w_out ∘ ctx) -> bf16
//  k5a: GEMM2 stats pass (A=M in regs); k5b: GEMM2 + LN write (A in regs)

#define NB    16
#define DIM   256
#define NSP   4096
#define LED   128
#define HID   256
#define NHEAD 8
#define SCALE 0.17677669529663687f

typedef __bf16 bf16x8 __attribute__((ext_vector_type(8)));
typedef float f32x4 __attribute__((ext_vector_type(4)));
typedef unsigned short us8 __attribute__((ext_vector_type(8)));
typedef unsigned short us4 __attribute__((ext_vector_type(4)));

__device__ __forceinline__ unsigned short f2bf(float f){
  unsigned u = __builtin_bit_cast(unsigned, f);
  u += 0x7fffu + ((u >> 16) & 1u);
  return (unsigned short)(u >> 16);
}
__device__ __forceinline__ float bf2f(unsigned short h){
  unsigned u = ((unsigned)h) << 16;
  return __builtin_bit_cast(float, u);
}
__device__ __forceinline__ bf16x8 ldb8(const unsigned short* p){
  us8 r = *(const us8*)p;
  return __builtin_bit_cast(bf16x8, r);
}
__device__ __forceinline__ f32x4 mfma16(bf16x8 a, bf16x8 b, f32x4 c){
  return __builtin_amdgcn_mfma_f32_16x16x32_bf16(a, b, c, 0, 0, 0);
}
__device__ __forceinline__ f32x4 mfma8(long a, long b, f32x4 c){
  return __builtin_amdgcn_mfma_f32_16x16x32_fp8_fp8(a, b, c, 0, 0, 0);
}
__device__ __forceinline__ void gl16(const unsigned short* g, unsigned short* l){
  __builtin_amdgcn_global_load_lds(
      (const __attribute__((address_space(1))) unsigned int*)g,
      (__attribute__((address_space(3))) unsigned int*)l,
      16, 0, 0);
}
__device__ __forceinline__ int pk4fp8(float v0, float v1, float v2, float v3){
  int r = __builtin_amdgcn_cvt_pk_fp8_f32(v0, v1, 0, false);
  r = __builtin_amdgcn_cvt_pk_fp8_f32(v2, v3, r, true);
  return r;
}

// ---------------- k01: x transpose + (w -> bf16, lk/lq) ----------------
__global__ __launch_bounds__(256) void k01_prep(
    const float* __restrict__ x, unsigned short* __restrict__ xt,
    const float* __restrict__ wqkv, const float* __restrict__ cond,
    const float* __restrict__ wlk, const float* __restrict__ blk,
    const float* __restrict__ wlq, const float* __restrict__ blq,
    unsigned short* __restrict__ whi,
    float* __restrict__ lk, float* __restrict__ lq)
{
  __shared__ float tile[64][65];
  const int t = threadIdx.x;
  if (blockIdx.x < 4){
    const int c0 = blockIdx.x*64, n0 = blockIdx.y*64, b = blockIdx.z;
    const int tr = t >> 6, tc = t & 63;
    const float* xp = x + ((size_t)b*DIM + c0)*NSP + n0;
    #pragma unroll
    for (int i=0;i<16;i++){
      const int cl = i*4 + tr;
      tile[cl][tc] = xp[(size_t)cl*NSP + tc];
    }
    __syncthreads();
    unsigned short* xtp = xt + ((size_t)b*NSP + n0)*DIM + c0;
    #pragma unroll
    for (int pass=0; pass<2; pass++){
      const int nl = pass*32 + (t>>3);
      const int c8 = (t&7)*8;
      us8 v;
      #pragma unroll
      for (int j=0;j<8;j++) v[j] = f2bf(tile[c8+j][nl]);
      *(us8*)&xtp[(size_t)nl*DIM + c8] = v;
    }
    return;
  }
  const int id = blockIdx.z*64 + blockIdx.y;
  if (id >= 320) return;
  const int idx = id*256 + t;
  if (idx < 49152){
    f32x4 w = *(const f32x4*)&wqkv[idx*4];
    us4 h;
    #pragma unroll
    for (int i=0;i<4;i++) h[i] = f2bf(w[i]);
    *(us4*)&whi[idx*4] = h;
  } else if (idx < 49152 + 32768){
    const int i2 = idx - 49152;
    const int d = i2 >> 2, sub = i2 & 3;
    const int which = (d >= NB*HID) ? 1 : 0;
    const int dd = d & (NB*HID - 1);
    const int b = dd >> 8, o = dd & 255;
    const float* wm = which ? wlq : wlk;
    const float* c = cond + b*LED;
    const float* wr = wm + o*LED;
    float s = 0.f;
    #pragma unroll
    for (int j=0;j<32;j++) s += c[sub*32+j]*wr[sub*32+j];
    s += __shfl_xor(s, 1);
    s += __shfl_xor(s, 2);
    if (sub == 0){
      const float bias = (which ? blq : blk)[o];
      (which ? lq : lk)[dd] = s + bias;
    }
  }
}

// ---------------- k2: GEMM1 BM=256, A in registers, B via gload_lds ----------------
__global__ __launch_bounds__(512) void k2_gemm1(
    const unsigned short* __restrict__ whi,
    const unsigned short* __restrict__ xt,
    const float* __restrict__ lkv, const float* __restrict__ lqv,
    unsigned short* __restrict__ qh,
    unsigned char* __restrict__ kexp, unsigned char* __restrict__ vout,
    float* __restrict__ ksum)
{
  __shared__ __align__(16) unsigned char smraw[36864];
  unsigned short* Bt   = (unsigned short*)smraw;            // [128][64] swizzled
  unsigned short* stg  = (unsigned short*)smraw;            // q: [64 n][256 dg] (32KB alias)
  unsigned char*  stg8 = (unsigned char*)smraw;             // kv: [256 dg][144 B]

  const int nt = blockIdx.x, mt = blockIdx.y, b = blockIdx.z;
  const int o0 = mt*256, n0 = nt*128;
  const int t = threadIdx.x, lane = t & 63, wv = t >> 6;    // 8 waves
  const int wr = wv >> 1, wc = wv & 1;
  const int cl = lane & 15, g = lane >> 4;

  f32x4 acc[4][4];
  const f32x4 z4 = {0.f,0.f,0.f,0.f};
  #pragma unroll
  for (int m=0;m<4;m++)
    #pragma unroll
    for (int n=0;n<4;n++) acc[m][n] = z4;

  const unsigned short* xb = xt + ((size_t)b*NSP + n0)*DIM;
  const int rowc = lane >> 3;
  const int gcol = 8*((lane & 7) ^ rowc);
  // A fragment row base (this thread's rows in W): o0 + wr*64 + m*16 + cl
  const unsigned short* abase = whi + (size_t)(o0 + wr*64 + cl)*DIM;

  for (int kt=0; kt<4; kt++){
    const int k0 = kt*64;
    __syncthreads();
    #pragma unroll
    for (int j=0;j<2;j++){
      const int rg = wv*2 + j;              // 0..15 -> B rows 0..127
      const int rr = rg*8 + rowc;
      gl16(&xb[(size_t)rr*DIM + k0 + gcol], &Bt[rg*512]);
    }
    // A fragments -> registers (L2-resident W)
    bf16x8 areg[2][4];
    #pragma unroll
    for (int kk=0;kk<2;kk++)
      #pragma unroll
      for (int m=0;m<4;m++)
        areg[kk][m] = ldb8(&abase[(size_t)(m*16)*DIM + k0 + kk*32 + g*8]);
    __syncthreads();
    #pragma unroll
    for (int kk=0; kk<2; kk++){
      const int ko = kk*32 + g*8;
      const int kosw = ko ^ ((cl & 7) << 3);
      bf16x8 bb[4];
      #pragma unroll
      for (int n=0;n<4;n++)
        bb[n] = ldb8(&Bt[(wc*64 + n*16 + cl)*64 + kosw]);
      #pragma unroll
      for (int m=0;m<4;m++)
        #pragma unroll
        for (int n=0;n<4;n++)
          acc[m][n] = mfma16(areg[kk][m], bb[n], acc[m][n]);
    }
  }

  __syncthreads();   // B reads done; LDS free for epilogue aliases

  if (mt == 0){
    // ---- Q: +lq, softmax over d=32; two n-half passes through stg [64][256]
    float lqr[4][4];
    #pragma unroll
    for (int m=0;m<4;m++)
      #pragma unroll
      for (int i=0;i<4;i++)
        lqr[m][i] = lqv[b*HID + wr*64 + m*16 + g*4 + i];
    #pragma unroll
    for (int h=0; h<2; h++){
      if (wc == h){
        #pragma unroll
        for (int j=0;j<2;j++){
          #pragma unroll
          for (int nf=0;nf<4;nf++){
            float e[8]; float mx = -1e30f;
            #pragma unroll
            for (int mm=0;mm<2;mm++)
              #pragma unroll
              for (int i=0;i<4;i++){
                const int m = 2*j+mm;
                const float v = acc[m][nf][i] + lqr[m][i];
                e[mm*4+i] = v; mx = fmaxf(mx, v);
              }
            mx = fmaxf(mx, __shfl_xor(mx, 16));
            mx = fmaxf(mx, __shfl_xor(mx, 32));
            float s = 0.f;
            #pragma unroll
            for (int q2=0;q2<8;q2++){ e[q2] = __expf(e[q2]-mx); s += e[q2]; }
            s += __shfl_xor(s, 16);
            s += __shfl_xor(s, 32);
            const float r = 1.f/s;
            const int nl = nf*16 + cl;
            const int rsw = (nl & 7) << 3;
            #pragma unroll
            for (int mm=0;mm<2;mm++){
              const int dg_local = wr*64 + (2*j+mm)*16 + g*4;
              us4 h4;
              #pragma unroll
              for (int i=0;i<4;i++) h4[i] = f2bf(e[mm*4+i]*r);
              *(us4*)&stg[nl*256 + (dg_local ^ rsw)] = h4;
            }
          }
        }
      }
      __syncthreads();
      #pragma unroll
      for (int it=0; it<4; it++){
        const int nl = it*16 + (t>>5);
        const int dg8 = (t&31)*8;
        us8 val = *(const us8*)&stg[nl*256 + (dg8 ^ ((nl&7)<<3))];
        *(us8*)&qh[((size_t)b*NSP + n0 + h*64 + nl)*HID + dg8] = val;
      }
      __syncthreads();
    }
  } else {
    // ---- K / V: stage fp8 [256 dg][144B rows, 128 cols used]
    const int isK = (mt == 1);
    #pragma unroll
    for (int m=0;m<4;m++)
      #pragma unroll
      for (int i=0;i<4;i++){
        const int dg = wr*64 + m*16 + g*4 + i;
        const int nb0 = wc*64 + cl;
        if (isK){
          const float lkval = lkv[b*HID + dg];
          const float v0 = __expf(acc[m][0][i] + lkval);
          const float v1 = __expf(acc[m][1][i] + lkval);
          const float v2 = __expf(acc[m][2][i] + lkval);
          const float v3 = __expf(acc[m][3][i] + lkval);
          const int pk = pk4fp8(v0, v1, v2, v3);
          stg8[dg*144 + nb0     ] = (unsigned char)(pk);
          stg8[dg*144 + nb0 + 16] = (unsigned char)(pk >> 8);
          stg8[dg*144 + nb0 + 32] = (unsigned char)(pk >> 16);
          stg8[dg*144 + nb0 + 48] = (unsigned char)(pk >> 24);
          float s = (v0 + v1) + (v2 + v3);
          s += __shfl_xor(s,1); s += __shfl_xor(s,2);
          s += __shfl_xor(s,4); s += __shfl_xor(s,8);
          if (cl == 0) atomicAdd(&ksum[b*HID + dg], s);
        } else {
          const int pk = pk4fp8(acc[m][0][i], acc[m][1][i],
                                acc[m][2][i], acc[m][3][i]);
          stg8[dg*144 + nb0     ] = (unsigned char)(pk);
          stg8[dg*144 + nb0 + 16] = (unsigned char)(pk >> 8);
          stg8[dg*144 + nb0 + 32] = (unsigned char)(pk >> 16);
          stg8[dg*144 + nb0 + 48] = (unsigned char)(pk >> 24);
        }
      }
    __syncthreads();
    unsigned char* obase = (isK ? kexp : vout) + ((size_t)b*HID)*NSP + n0;
    const int lane8 = t & 7;
    const int rowid = t >> 3;          // 0..63
    #pragma unroll
    for (int i2=0;i2<4;i2++){
      const int dg = i2*64 + rowid;
      us8 val = *(const us8*)&stg8[dg*144 + lane8*16];
      *(us8*)&obase[(size_t)dg*NSP + lane8*16] = val;
    }
  }
}

// ---------------- k3: context partials (fp8 MFMA) ----------------
__global__ __launch_bounds__(256) void k3_ctx(
    const unsigned char* __restrict__ kexp, const unsigned char* __restrict__ vv,
    float* __restrict__ ctxp)
{
  const int half = blockIdx.x, h = blockIdx.y, b = blockIdx.z;
  const int t = threadIdx.x, lane = t&63, wv = t>>6;
  const int cl = lane&15, g = lane>>4;
  const int nstart = half*2048 + wv*512;
  f32x4 acc[2][2];
  const f32x4 z4 = {0.f,0.f,0.f,0.f};
  acc[0][0]=z4; acc[0][1]=z4; acc[1][0]=z4; acc[1][1]=z4;
  const unsigned char* kb = kexp + ((size_t)b*HID + h*32)*NSP;
  const unsigned char* vb = vv   + ((size_t)b*HID + h*32)*NSP;
  for (int ks=0; ks<16; ks++){
    const int k = nstart + ks*32 + g*8;
    long a0 = *(const long*)&kb[(size_t)(cl)   *NSP + k];
    long a1 = *(const long*)&kb[(size_t)(16+cl)*NSP + k];
    long b0 = *(const long*)&vb[(size_t)(cl)   *NSP + k];
    long b1 = *(const long*)&vb[(size_t)(16+cl)*NSP + k];
    acc[0][0] = mfma8(a0,b0,acc[0][0]);
    acc[0][1] = mfma8(a0,b1,acc[0][1]);
    acc[1][0] = mfma8(a1,b0,acc[1][0]);
    acc[1][1] = mfma8(a1,b1,acc[1][1]);
  }
  float* outp = ctxp + ((((size_t)b*NHEAD + h)*2 + half)*4 + wv)*1024;
  #pragma unroll
  for (int dm=0;dm<2;dm++)
    #pragma unroll
    for (int em=0;em<2;em++)
      #pragma unroll
      for (int i=0;i<4;i++)
        outp[(dm*16 + g*4 + i)*32 + em*16 + cl] = acc[dm][em][i];
}

// ---------------- k4: M = scale/ksum * (w_out compose context) -> bf16 ----------------
__global__ __launch_bounds__(256) void k4_m(
    const float* __restrict__ ctxp, const float* __restrict__ ksum,
    const float* __restrict__ wout,
    unsigned short* __restrict__ mhi)
{
  const int h = blockIdx.x, b = blockIdx.y;
  __shared__ float ctxl[32][32];
  __shared__ float rkn[32];
  const int t = threadIdx.x;
  const float* base = ctxp + (((size_t)b*NHEAD + h)*8)*1024;
  #pragma unroll
  for (int r=0;r<4;r++){
    const int de = r*256 + t;
    float s = 0.f;
    #pragma unroll
    for (int p=0;p<8;p++) s += base[p*1024 + de];
    ctxl[de>>5][de&31] = s;
  }
  if (t < 32) rkn[t] = SCALE / ksum[b*HID + h*32 + t];
  __syncthreads();
  float w[32];
  const float* wrow = wout + (size_t)t*HID + h*32;
  #pragma unroll
  for (int el=0;el<32;el++) w[el] = wrow[el];
  for (int dl=0; dl<32; dl++){
    float s = 0.f;
    #pragma unroll
    for (int el=0;el<32;el++) s += w[el]*ctxl[dl][el];
    s *= rkn[dl];
    mhi[((size_t)b*HID + t)*HID + h*32 + dl] = f2bf(s);
  }
}

// ---------------- k5a: GEMM2 stats pass (A=M in regs, no y write) ----------------
__global__ __launch_bounds__(256) void k5a_stats(
    const unsigned short* __restrict__ mhi,
    const unsigned short* __restrict__ qhp, const float* __restrict__ bout,
    float* __restrict__ bsum, float* __restrict__ bssq)
{
  __shared__ __align__(16) unsigned char smraw[16384];
  unsigned short* Bh = (unsigned short*)smraw;     // [128][64]
  __shared__ float red[8];

  const int nt = blockIdx.x, mt = blockIdx.y, b = blockIdx.z;
  const int o0 = mt*128, n0 = nt*128;
  const int t = threadIdx.x, lane = t&63, wv = t>>6;
  const int wr = wv>>1, wc = wv&1;
  const int cl = lane&15, g = lane>>4;

  f32x4 acc[4][4];
  const f32x4 z4 = {0.f,0.f,0.f,0.f};
  #pragma unroll
  for (int m=0;m<4;m++)
    #pragma unroll
    for (int n=0;n<4;n++) acc[m][n] = z4;

  const unsigned short* ab = mhi + (size_t)b*HID*HID + (size_t)(o0 + wr*64 + cl)*HID;
  const unsigned short* bb_h = qhp + ((size_t)b*NSP + n0)*HID;
  const int rowc = lane >> 3;
  const int gcol = 8*((lane & 7) ^ rowc);

  for (int kt=0; kt<4; kt++){
    const int k0 = kt*64;
    __syncthreads();
    #pragma unroll
    for (int j=0;j<4;j++){
      const int rg = wv*4 + j;
      const int rr = rg*8 + rowc;
      gl16(&bb_h[(size_t)rr*HID + k0 + gcol], &Bh[rg*512]);
    }
    bf16x8 areg[2][4];
    #pragma unroll
    for (int kk=0;kk<2;kk++)
      #pragma unroll
      for (int m=0;m<4;m++)
        areg[kk][m] = ldb8(&ab[(size_t)(m*16)*HID + k0 + kk*32 + g*8]);
    __syncthreads();
    #pragma unroll
    for (int kk=0;kk<2;kk++){
      const int ko = kk*32 + g*8;
      const int kosw = ko ^ ((cl & 7) << 3);
      bf16x8 bh[4];
      #pragma unroll
      for (int n=0;n<4;n++)
        bh[n] = ldb8(&Bh[(wc*64 + n*16 + cl)*64 + kosw]);
      #pragma unroll
      for (int m=0;m<4;m++)
        #pragma unroll
        for (int n=0;n<4;n++)
          acc[m][n] = mfma16(areg[kk][m], bh[n], acc[m][n]);
    }
  }

  float lsum = 0.f, lss = 0.f;
  #pragma unroll
  for (int m=0;m<4;m++)
    #pragma unroll
    for (int i=0;i<4;i++){
      const float bo = bout[o0 + wr*64 + m*16 + g*4 + i];
      #pragma unroll
      for (int nf=0;nf<4;nf++){
        const float v = acc[m][nf][i] + bo;
        lsum += v; lss += v*v;
      }
    }
  #pragma unroll
  for (int sft=1; sft<64; sft<<=1){
    lsum += __shfl_xor(lsum, sft);
    lss  += __shfl_xor(lss,  sft);
  }
  if (lane == 0){ red[wv] = lsum; red[4+wv] = lss; }
  __syncthreads();
  if (t == 0){
    atomicAdd(&bsum[b], red[0]+red[1]+red[2]+red[3]);
    atomicAdd(&bssq[b], red[4]+red[5]+red[6]+red[7]);
  }
}

// ---------------- k5b: GEMM2 (A=M in regs) + fused LayerNorm write ----------------
__global__ __launch_bounds__(256) void k5b_write(
    const unsigned short* __restrict__ mhi,
    const unsigned short* __restrict__ qhp, const float* __restrict__ bout,
    const float* __restrict__ bsum, const float* __restrict__ bssq,
    const float* __restrict__ gamma, const float* __restrict__ beta,
    float* __restrict__ out)
{
  __shared__ __align__(16) unsigned char smraw[32768];
  unsigned short* Bh = (unsigned short*)smraw;     // [128][64]
  float* stg = (float*)smraw;                      // [64][128] f32 swizzled alias

  const int nt = blockIdx.x, mt = blockIdx.y, b = blockIdx.z;
  const int o0 = mt*128, n0 = nt*128;
  const int t = threadIdx.x, lane = t&63, wv = t>>6;
  const int wr = wv>>1, wc = wv&1;
  const int cl = lane&15, g = lane>>4;

  f32x4 acc[4][4];
  const f32x4 z4 = {0.f,0.f,0.f,0.f};
  #pragma unroll
  for (int m=0;m<4;m++)
    #pragma unroll
    for (int n=0;n<4;n++) acc[m][n] = z4;

  const unsigned short* ab = mhi + (size_t)b*HID*HID + (size_t)(o0 + wr*64 + cl)*HID;
  const unsigned short* bb_h = qhp + ((size_t)b*NSP + n0)*HID;
  const int rowc = lane >> 3;
  const int gcol = 8*((lane & 7) ^ rowc);

  for (int kt=0; kt<4; kt++){
    const int k0 = kt*64;
    __syncthreads();
    #pragma unroll
    for (int j=0;j<4;j++){
      const int rg = wv*4 + j;
      const int rr = rg*8 + rowc;
      gl16(&bb_h[(size_t)rr*HID + k0 + gcol], &Bh[rg*512]);
    }
    bf16x8 areg[2][4];
    #pragma unroll
    for (int kk=0;kk<2;kk++)
      #pragma unroll
      for (int m=0;m<4;m++)
        areg[kk][m] = ldb8(&ab[(size_t)(m*16)*HID + k0 + kk*32 + g*8]);
    __syncthreads();
    #pragma unroll
    for (int kk=0;kk<2;kk++){
      const int ko = kk*32 + g*8;
      const int kosw = ko ^ ((cl & 7) << 3);
      bf16x8 bh[4];
      #pragma unroll
      for (int n=0;n<4;n++)
        bh[n] = ldb8(&Bh[(wc*64 + n*16 + cl)*64 + kosw]);
      #pragma unroll
      for (int m=0;m<4;m++)
        #pragma unroll
        for (int n=0;n<4;n++)
          acc[m][n] = mfma16(areg[kk][m], bh[n], acc[m][n]);
    }
  }

  // LN coefficients: out = acc*ga + (beta + (bout-mean)*ga)
  const float inv = 1.f/1048576.f;
  const float mean = bsum[b]*inv;
  const float var  = bssq[b]*inv - mean*mean;
  const float ri = rsqrtf(var + 1e-5f);
  float gav[4][4], bev[4][4];
  #pragma unroll
  for (int m=0;m<4;m++)
    #pragma unroll
    for (int i=0;i<4;i++){
      const int o = o0 + wr*64 + m*16 + g*4 + i;
      const float ga = gamma[o]*ri;
      gav[m][i] = ga;
      bev[m][i] = beta[o] + (bout[o]-mean)*ga;
    }

  #pragma unroll
  for (int p=0;p<2;p++){
    __syncthreads();
    #pragma unroll
    for (int mm=0;mm<2;mm++){
      const int m = 2*p+mm;
      #pragma unroll
      for (int nf=0;nf<4;nf++)
        #pragma unroll
        for (int i=0;i<4;i++){
          const int lr = wr*32 + mm*16 + g*4 + i;
          const int col = wc*64 + nf*16 + cl;
          stg[lr*128 + (col ^ ((lr&7)<<2))] = acc[m][nf][i]*gav[m][i] + bev[m][i];
        }
    }
    __syncthreads();
    #pragma unroll
    for (int i2=0;i2<8;i2++){
      const int lr = wv*16 + i2*2 + (lane>>5);
      const int colw = (lane&31)*4;
      f32x4 v = *(const f32x4*)&stg[lr*128 + (colw ^ ((lr&7)<<2))];
      const int dg = o0 + (lr>>5)*64 + p*32 + (lr&31);
      *(f32x4*)&out[((size_t)b*HID + dg)*NSP + n0 + colw] = v;
    }
  }
}

// ---------------- workspace layout (bytes) ----------------
#define OFF_XT     0ull           // ushort [16][4096][256]  32MB
#define OFF_QH     33554432ull    // ushort [16][4096][256]  32MB
#define OFF_CTXP   67108864ull    // float [16][8][8][1024]  4MB
#define OFF_MH     71303168ull    // ushort [16][256][256]   2MB
#define OFF_LK     73400320ull    // float [16][256]
#define OFF_LQ     73416704ull
#define OFF_WHI    73433088ull    // ushort [768][256]
#define OFF_KSUM   73826304ull    // float [16][256]
#define OFF_BSUM   73842688ull    // float [16]
#define OFF_BSSQ   73842752ull    // float [16]

extern "C" void kernel_launch(void* const* d_in, const int* in_sizes, int n_in,
                              void* d_out, int out_size, void* d_ws, size_t ws_size,
                              hipStream_t stream) {
  const float* x     = (const float*)d_in[0];
  const float* cond  = (const float*)d_in[1];
  const float* wqkv  = (const float*)d_in[2];
  const float* wlk   = (const float*)d_in[3];
  const float* blk   = (const float*)d_in[4];
  const float* wlq   = (const float*)d_in[5];
  const float* blq   = (const float*)d_in[6];
  const float* wout  = (const float*)d_in[7];
  const float* bout  = (const float*)d_in[8];
  const float* gamma = (const float*)d_in[9];
  const float* beta  = (const float*)d_in[10];

  char* ws = (char*)d_ws;
  unsigned short* xt   = (unsigned short*)(ws + OFF_XT);
  unsigned short* qh   = (unsigned short*)(ws + OFF_QH);
  float*          ctxp = (float*)(ws + OFF_CTXP);
  unsigned short* mhi  = (unsigned short*)(ws + OFF_MH);
  float*          lk   = (float*)(ws + OFF_LK);
  float*          lq   = (float*)(ws + OFF_LQ);
  unsigned short* whi  = (unsigned short*)(ws + OFF_WHI);
  float*          ksum = (float*)(ws + OFF_KSUM);
  float*          bsum = (float*)(ws + OFF_BSUM);
  float*          bssq = (float*)(ws + OFF_BSSQ);

  // d_out doubles as scratch for fp8 kexp/v (consumed by k3 before k5b writes y)
  unsigned char* kexp = (unsigned char*)d_out;                // 16MB
  unsigned char* vscr = (unsigned char*)d_out + 16777216;     // 16MB
  float*         y    = (float*)d_out;

  hipMemsetAsync(ws + OFF_KSUM, 0, 16384 + 128, stream);

  k01_prep <<<dim3(5,64,16), 256, 0, stream>>>(x, xt, wqkv, cond, wlk, blk, wlq, blq, whi, lk, lq);
  k2_gemm1 <<<dim3(32,3,16), 512, 0, stream>>>(whi, xt, lk, lq, qh, kexp, vscr, ksum);
  k3_ctx   <<<dim3(2,8,16), 256, 0, stream>>>(kexp, vscr, ctxp);
  k4_m     <<<dim3(8,16), 256, 0, stream>>>(ctxp, ksum, wout, mhi);
  k5a_stats<<<dim3(32,2,16), 256, 0, stream>>>(mhi, qh, bout, bsum, bssq);
  k5b_write<<<dim3(32,2,16), 256, 0, stream>>>(mhi, qh, bout, bsum, bssq, gamma, beta, y);
}

// Round 19
// 141.898 us; speedup vs baseline: 1.4498x; 1.4498x over previous
//
#include <hip/hip_runtime.h>
#include <hip/hip_fp8.h>

// LinearCrossAttentionAdd on MI355X (gfx950)  — r17 configuration (session best)
// Pipeline:
//  k01: [x<4] x (b,c,n) f32 -> xt (b,n,c) bf16 ; [x==4] w->bf16, lk/lq dots
//  k2: GEMM1 per batch BM=256 (512 thr, 48KB LDS, mt = q|k|v):
//        q: +lq, softmax over d -> qh [n][dg] bf16
//        k: exp(k+lk) -> fp8 (hw cvt_pk) [dg][n]; ksum = sum of UNquantized
//        v: fp8 [dg][n]
//  k3: ctx partials (fp8 MFMA)
//  k4: M = scale/ksum * (w_out ∘ ctx) -> bf16
//  k5a: GEMM2 stats pass; k5b: GEMM2 + fused LayerNorm -> d_out f32

#define NB    16
#define DIM   256
#define NSP   4096
#define LED   128
#define HID   256
#define NHEAD 8
#define SCALE 0.17677669529663687f

typedef __bf16 bf16x8 __attribute__((ext_vector_type(8)));
typedef float f32x4 __attribute__((ext_vector_type(4)));
typedef unsigned short us8 __attribute__((ext_vector_type(8)));
typedef unsigned short us4 __attribute__((ext_vector_type(4)));

__device__ __forceinline__ unsigned short f2bf(float f){
  unsigned u = __builtin_bit_cast(unsigned, f);
  u += 0x7fffu + ((u >> 16) & 1u);
  return (unsigned short)(u >> 16);
}
__device__ __forceinline__ float bf2f(unsigned short h){
  unsigned u = ((unsigned)h) << 16;
  return __builtin_bit_cast(float, u);
}
__device__ __forceinline__ bf16x8 ldb8(const unsigned short* p){
  us8 r = *(const us8*)p;
  return __builtin_bit_cast(bf16x8, r);
}
__device__ __forceinline__ f32x4 mfma16(bf16x8 a, bf16x8 b, f32x4 c){
  return __builtin_amdgcn_mfma_f32_16x16x32_bf16(a, b, c, 0, 0, 0);
}
__device__ __forceinline__ f32x4 mfma8(long a, long b, f32x4 c){
  return __builtin_amdgcn_mfma_f32_16x16x32_fp8_fp8(a, b, c, 0, 0, 0);
}
__device__ __forceinline__ void gl16(const unsigned short* g, unsigned short* l){
  __builtin_amdgcn_global_load_lds(
      (const __attribute__((address_space(1))) unsigned int*)g,
      (__attribute__((address_space(3))) unsigned int*)l,
      16, 0, 0);
}
__device__ __forceinline__ int pk4fp8(float v0, float v1, float v2, float v3){
  int r = __builtin_amdgcn_cvt_pk_fp8_f32(v0, v1, 0, false);
  r = __builtin_amdgcn_cvt_pk_fp8_f32(v2, v3, r, true);
  return r;
}

// ---------------- k01: x transpose + (w -> bf16, lk/lq) ----------------
__global__ __launch_bounds__(256) void k01_prep(
    const float* __restrict__ x, unsigned short* __restrict__ xt,
    const float* __restrict__ wqkv, const float* __restrict__ cond,
    const float* __restrict__ wlk, const float* __restrict__ blk,
    const float* __restrict__ wlq, const float* __restrict__ blq,
    unsigned short* __restrict__ whi,
    float* __restrict__ lk, float* __restrict__ lq)
{
  __shared__ float tile[64][65];
  const int t = threadIdx.x;
  if (blockIdx.x < 4){
    const int c0 = blockIdx.x*64, n0 = blockIdx.y*64, b = blockIdx.z;
    const int tr = t >> 6, tc = t & 63;
    const float* xp = x + ((size_t)b*DIM + c0)*NSP + n0;
    #pragma unroll
    for (int i=0;i<16;i++){
      const int cl = i*4 + tr;
      tile[cl][tc] = xp[(size_t)cl*NSP + tc];
    }
    __syncthreads();
    unsigned short* xtp = xt + ((size_t)b*NSP + n0)*DIM + c0;
    #pragma unroll
    for (int pass=0; pass<2; pass++){
      const int nl = pass*32 + (t>>3);
      const int c8 = (t&7)*8;
      us8 v;
      #pragma unroll
      for (int j=0;j<8;j++) v[j] = f2bf(tile[c8+j][nl]);
      *(us8*)&xtp[(size_t)nl*DIM + c8] = v;
    }
    return;
  }
  const int id = blockIdx.z*64 + blockIdx.y;
  if (id >= 320) return;
  const int idx = id*256 + t;
  if (idx < 49152){
    f32x4 w = *(const f32x4*)&wqkv[idx*4];
    us4 h;
    #pragma unroll
    for (int i=0;i<4;i++) h[i] = f2bf(w[i]);
    *(us4*)&whi[idx*4] = h;
  } else if (idx < 49152 + 32768){
    const int i2 = idx - 49152;
    const int d = i2 >> 2, sub = i2 & 3;
    const int which = (d >= NB*HID) ? 1 : 0;
    const int dd = d & (NB*HID - 1);
    const int b = dd >> 8, o = dd & 255;
    const float* wm = which ? wlq : wlk;
    const float* c = cond + b*LED;
    const float* wr = wm + o*LED;
    float s = 0.f;
    #pragma unroll
    for (int j=0;j<32;j++) s += c[sub*32+j]*wr[sub*32+j];
    s += __shfl_xor(s, 1);
    s += __shfl_xor(s, 2);
    if (sub == 0){
      const float bias = (which ? blq : blk)[o];
      (which ? lq : lk)[dd] = s + bias;
    }
  }
}

// ---------------- k2: GEMM1 BM=256 (512 thr), fused epilogues ----------------
__global__ __launch_bounds__(512) void k2_gemm1(
    const unsigned short* __restrict__ whi,
    const unsigned short* __restrict__ xt,
    const float* __restrict__ lkv, const float* __restrict__ lqv,
    unsigned short* __restrict__ qh,
    unsigned char* __restrict__ kexp, unsigned char* __restrict__ vout,
    float* __restrict__ ksum)
{
  __shared__ __align__(16) unsigned char smraw[49152];
  unsigned short* At   = (unsigned short*)smraw;            // [256][64] bf16 swizzled
  unsigned short* Bt   = (unsigned short*)(smraw + 32768);  // [128][64]
  unsigned short* stg  = (unsigned short*)smraw;            // q: [64 n][256 dg] us (per pass)
  unsigned char*  stg8 = (unsigned char*)smraw;             // kv: [256 dg][144 B]

  const int nt = blockIdx.x, mt = blockIdx.y, b = blockIdx.z;
  const int o0 = mt*256, n0 = nt*128;
  const int t = threadIdx.x, lane = t & 63, wv = t >> 6;    // 8 waves
  const int wr = wv >> 1, wc = wv & 1;                       // 4x2 wave grid
  const int cl = lane & 15, g = lane >> 4;

  f32x4 acc[4][4];
  const f32x4 z4 = {0.f,0.f,0.f,0.f};
  #pragma unroll
  for (int m=0;m<4;m++)
    #pragma unroll
    for (int n=0;n<4;n++) acc[m][n] = z4;

  const unsigned short* xb = xt + ((size_t)b*NSP + n0)*DIM;
  const int rowc = lane >> 3;
  const int gcol = 8*((lane & 7) ^ rowc);

  for (int kt=0; kt<4; kt++){
    const int k0 = kt*64;
    __syncthreads();
    #pragma unroll
    for (int j=0;j<4;j++){
      const int rg = wv*4 + j;              // 0..31 -> A rows 0..255
      const int rr = rg*8 + rowc;
      gl16(&whi[(size_t)(o0+rr)*DIM + k0 + gcol], &At[rg*512]);
    }
    #pragma unroll
    for (int j=0;j<2;j++){
      const int rg = wv*2 + j;              // 0..15 -> B rows 0..127
      const int rr = rg*8 + rowc;
      gl16(&xb[(size_t)rr*DIM + k0 + gcol], &Bt[rg*512]);
    }
    __syncthreads();
    #pragma unroll
    for (int kk=0; kk<2; kk++){
      const int ko = kk*32 + g*8;
      const int kosw = ko ^ ((cl & 7) << 3);
      bf16x8 a1[4], bb[4];
      #pragma unroll
      for (int m=0;m<4;m++)
        a1[m] = ldb8(&At[(wr*64 + m*16 + cl)*64 + kosw]);
      #pragma unroll
      for (int n=0;n<4;n++)
        bb[n] = ldb8(&Bt[(wc*64 + n*16 + cl)*64 + kosw]);
      #pragma unroll
      for (int m=0;m<4;m++)
        #pragma unroll
        for (int n=0;n<4;n++)
          acc[m][n] = mfma16(a1[m], bb[n], acc[m][n]);
    }
  }

  __syncthreads();   // all fragment reads done; LDS free for epilogue aliases

  if (mt == 0){
    // ---- Q: +lq, softmax over d=32; two n-half passes through stg [64][256]
    float lqr[4][4];
    #pragma unroll
    for (int m=0;m<4;m++)
      #pragma unroll
      for (int i=0;i<4;i++)
        lqr[m][i] = lqv[b*HID + wr*64 + m*16 + g*4 + i];
    #pragma unroll
    for (int h=0; h<2; h++){
      if (wc == h){
        #pragma unroll
        for (int j=0;j<2;j++){
          #pragma unroll
          for (int nf=0;nf<4;nf++){
            float e[8]; float mx = -1e30f;
            #pragma unroll
            for (int mm=0;mm<2;mm++)
              #pragma unroll
              for (int i=0;i<4;i++){
                const int m = 2*j+mm;
                const float v = acc[m][nf][i] + lqr[m][i];
                e[mm*4+i] = v; mx = fmaxf(mx, v);
              }
            mx = fmaxf(mx, __shfl_xor(mx, 16));
            mx = fmaxf(mx, __shfl_xor(mx, 32));
            float s = 0.f;
            #pragma unroll
            for (int q2=0;q2<8;q2++){ e[q2] = __expf(e[q2]-mx); s += e[q2]; }
            s += __shfl_xor(s, 16);
            s += __shfl_xor(s, 32);
            const float r = 1.f/s;
            const int nl = nf*16 + cl;            // 0..63 within pass
            const int rsw = (nl & 7) << 3;
            #pragma unroll
            for (int mm=0;mm<2;mm++){
              const int dg_local = wr*64 + (2*j+mm)*16 + g*4;   // 0..255
              us4 h4;
              #pragma unroll
              for (int i=0;i<4;i++) h4[i] = f2bf(e[mm*4+i]*r);
              *(us4*)&stg[nl*256 + (dg_local ^ rsw)] = h4;
            }
          }
        }
      }
      __syncthreads();
      // copy out 64 n-rows x 256 dg (512B rows)
      #pragma unroll
      for (int it=0; it<4; it++){
        const int nl = it*16 + (t>>5);
        const int dg8 = (t&31)*8;
        us8 val = *(const us8*)&stg[nl*256 + (dg8 ^ ((nl&7)<<3))];
        *(us8*)&qh[((size_t)b*NSP + n0 + h*64 + nl)*HID + dg8] = val;
      }
      __syncthreads();
    }
  } else {
    // ---- K / V (full 256 dg): stage fp8 [256 dg][144B rows, 128 cols used]
    const int isK = (mt == 1);
    #pragma unroll
    for (int m=0;m<4;m++)
      #pragma unroll
      for (int i=0;i<4;i++){
        const int dg = wr*64 + m*16 + g*4 + i;     // 0..255
        const int nb0 = wc*64 + cl;
        if (isK){
          const float lkval = lkv[b*HID + dg];
          const float v0 = __expf(acc[m][0][i] + lkval);
          const float v1 = __expf(acc[m][1][i] + lkval);
          const float v2 = __expf(acc[m][2][i] + lkval);
          const float v3 = __expf(acc[m][3][i] + lkval);
          const int pk = pk4fp8(v0, v1, v2, v3);
          stg8[dg*144 + nb0     ] = (unsigned char)(pk);
          stg8[dg*144 + nb0 + 16] = (unsigned char)(pk >> 8);
          stg8[dg*144 + nb0 + 32] = (unsigned char)(pk >> 16);
          stg8[dg*144 + nb0 + 48] = (unsigned char)(pk >> 24);
          float s = (v0 + v1) + (v2 + v3);         // unquantized sum
          s += __shfl_xor(s,1); s += __shfl_xor(s,2);
          s += __shfl_xor(s,4); s += __shfl_xor(s,8);
          if (cl == 0) atomicAdd(&ksum[b*HID + dg], s);
        } else {
          const int pk = pk4fp8(acc[m][0][i], acc[m][1][i],
                                acc[m][2][i], acc[m][3][i]);
          stg8[dg*144 + nb0     ] = (unsigned char)(pk);
          stg8[dg*144 + nb0 + 16] = (unsigned char)(pk >> 8);
          stg8[dg*144 + nb0 + 32] = (unsigned char)(pk >> 16);
          stg8[dg*144 + nb0 + 48] = (unsigned char)(pk >> 24);
        }
      }
    __syncthreads();
    // copy-out: 256 rows x 128B; 512 thr x 16B = 64 rows/iter, 4 iters
    unsigned char* obase = (isK ? kexp : vout) + ((size_t)b*HID)*NSP + n0;
    const int lane8 = t & 7;
    const int rowid = t >> 3;          // 0..63
    #pragma unroll
    for (int i2=0;i2<4;i2++){
      const int dg = i2*64 + rowid;
      us8 val = *(const us8*)&stg8[dg*144 + lane8*16];
      *(us8*)&obase[(size_t)dg*NSP + lane8*16] = val;
    }
  }
}

// ---------------- k3: context partials (fp8 MFMA) ----------------
__global__ __launch_bounds__(256) void k3_ctx(
    const unsigned char* __restrict__ kexp, const unsigned char* __restrict__ vv,
    float* __restrict__ ctxp)
{
  const int half = blockIdx.x, h = blockIdx.y, b = blockIdx.z;
  const int t = threadIdx.x, lane = t&63, wv = t>>6;
  const int cl = lane&15, g = lane>>4;
  const int nstart = half*2048 + wv*512;
  f32x4 acc[2][2];
  const f32x4 z4 = {0.f,0.f,0.f,0.f};
  acc[0][0]=z4; acc[0][1]=z4; acc[1][0]=z4; acc[1][1]=z4;
  const unsigned char* kb = kexp + ((size_t)b*HID + h*32)*NSP;
  const unsigned char* vb = vv   + ((size_t)b*HID + h*32)*NSP;
  for (int ks=0; ks<16; ks++){
    const int k = nstart + ks*32 + g*8;
    long a0 = *(const long*)&kb[(size_t)(cl)   *NSP + k];
    long a1 = *(const long*)&kb[(size_t)(16+cl)*NSP + k];
    long b0 = *(const long*)&vb[(size_t)(cl)   *NSP + k];
    long b1 = *(const long*)&vb[(size_t)(16+cl)*NSP + k];
    acc[0][0] = mfma8(a0,b0,acc[0][0]);
    acc[0][1] = mfma8(a0,b1,acc[0][1]);
    acc[1][0] = mfma8(a1,b0,acc[1][0]);
    acc[1][1] = mfma8(a1,b1,acc[1][1]);
  }
  float* outp = ctxp + ((((size_t)b*NHEAD + h)*2 + half)*4 + wv)*1024;
  #pragma unroll
  for (int dm=0;dm<2;dm++)
    #pragma unroll
    for (int em=0;em<2;em++)
      #pragma unroll
      for (int i=0;i<4;i++)
        outp[(dm*16 + g*4 + i)*32 + em*16 + cl] = acc[dm][em][i];
}

// ---------------- k4: M = scale/ksum * (w_out compose context) -> bf16 ----------------
__global__ __launch_bounds__(256) void k4_m(
    const float* __restrict__ ctxp, const float* __restrict__ ksum,
    const float* __restrict__ wout,
    unsigned short* __restrict__ mhi)
{
  const int h = blockIdx.x, b = blockIdx.y;
  __shared__ float ctxl[32][32];
  __shared__ float rkn[32];
  const int t = threadIdx.x;
  const float* base = ctxp + (((size_t)b*NHEAD + h)*8)*1024;
  #pragma unroll
  for (int r=0;r<4;r++){
    const int de = r*256 + t;
    float s = 0.f;
    #pragma unroll
    for (int p=0;p<8;p++) s += base[p*1024 + de];
    ctxl[de>>5][de&31] = s;
  }
  if (t < 32) rkn[t] = SCALE / ksum[b*HID + h*32 + t];
  __syncthreads();
  float w[32];
  const float* wrow = wout + (size_t)t*HID + h*32;
  #pragma unroll
  for (int el=0;el<32;el++) w[el] = wrow[el];
  for (int dl=0; dl<32; dl++){
    float s = 0.f;
    #pragma unroll
    for (int el=0;el<32;el++) s += w[el]*ctxl[dl][el];
    s *= rkn[dl];
    mhi[((size_t)b*HID + t)*HID + h*32 + dl] = f2bf(s);
  }
}

// ---------------- k5a: GEMM2 stats pass (no y write) ----------------
__global__ __launch_bounds__(256) void k5a_stats(
    const unsigned short* __restrict__ mhi,
    const unsigned short* __restrict__ qhp, const float* __restrict__ bout,
    float* __restrict__ bsum, float* __restrict__ bssq)
{
  __shared__ __align__(16) unsigned char smraw[32768];
  unsigned short* Ah = (unsigned short*)smraw;
  unsigned short* Bh = (unsigned short*)(smraw + 16384);
  __shared__ float red[8];

  const int nt = blockIdx.x, mt = blockIdx.y, b = blockIdx.z;
  const int o0 = mt*128, n0 = nt*128;
  const int t = threadIdx.x, lane = t&63, wv = t>>6;
  const int wr = wv>>1, wc = wv&1;
  const int cl = lane&15, g = lane>>4;

  f32x4 acc[4][4];
  const f32x4 z4 = {0.f,0.f,0.f,0.f};
  #pragma unroll
  for (int m=0;m<4;m++)
    #pragma unroll
    for (int n=0;n<4;n++) acc[m][n] = z4;

  const unsigned short* ab_h = mhi + (size_t)b*HID*HID;
  const unsigned short* bb_h = qhp + ((size_t)b*NSP + n0)*HID;
  const int rowc = lane >> 3;
  const int gcol = 8*((lane & 7) ^ rowc);

  for (int kt=0; kt<4; kt++){
    const int k0 = kt*64;
    __syncthreads();
    #pragma unroll
    for (int j=0;j<4;j++){
      const int rg = wv*4 + j;
      const int rr = rg*8 + rowc;
      gl16(&ab_h[(size_t)(o0+rr)*HID + k0 + gcol], &Ah[rg*512]);
      gl16(&bb_h[(size_t)rr*HID      + k0 + gcol], &Bh[rg*512]);
    }
    __syncthreads();
    #pragma unroll
    for (int kk=0;kk<2;kk++){
      const int ko = kk*32 + g*8;
      const int kosw = ko ^ ((cl & 7) << 3);
      bf16x8 ah[4], bh[4];
      #pragma unroll
      for (int m=0;m<4;m++)
        ah[m] = ldb8(&Ah[(wr*64 + m*16 + cl)*64 + kosw]);
      #pragma unroll
      for (int n=0;n<4;n++)
        bh[n] = ldb8(&Bh[(wc*64 + n*16 + cl)*64 + kosw]);
      #pragma unroll
      for (int m=0;m<4;m++)
        #pragma unroll
        for (int n=0;n<4;n++)
          acc[m][n] = mfma16(ah[m], bh[n], acc[m][n]);
    }
  }

  float lsum = 0.f, lss = 0.f;
  #pragma unroll
  for (int m=0;m<4;m++)
    #pragma unroll
    for (int i=0;i<4;i++){
      const float bo = bout[o0 + wr*64 + m*16 + g*4 + i];
      #pragma unroll
      for (int nf=0;nf<4;nf++){
        const float v = acc[m][nf][i] + bo;
        lsum += v; lss += v*v;
      }
    }
  #pragma unroll
  for (int sft=1; sft<64; sft<<=1){
    lsum += __shfl_xor(lsum, sft);
    lss  += __shfl_xor(lss,  sft);
  }
  if (lane == 0){ red[wv] = lsum; red[4+wv] = lss; }
  __syncthreads();
  if (t == 0){
    atomicAdd(&bsum[b], red[0]+red[1]+red[2]+red[3]);
    atomicAdd(&bssq[b], red[4]+red[5]+red[6]+red[7]);
  }
}

// ---------------- k5b: GEMM2 (M-hi) + fused LayerNorm write ----------------
__global__ __launch_bounds__(256) void k5b_write(
    const unsigned short* __restrict__ mhi,
    const unsigned short* __restrict__ qhp, const float* __restrict__ bout,
    const float* __restrict__ bsum, const float* __restrict__ bssq,
    const float* __restrict__ gamma, const float* __restrict__ beta,
    float* __restrict__ out)
{
  __shared__ __align__(16) unsigned char smraw[32768];
  unsigned short* Ah = (unsigned short*)smraw;             // [128][64]
  unsigned short* Bh = (unsigned short*)(smraw + 16384);
  float* stg = (float*)smraw;                              // [64][128] f32 swizzled alias

  const int nt = blockIdx.x, mt = blockIdx.y, b = blockIdx.z;
  const int o0 = mt*128, n0 = nt*128;
  const int t = threadIdx.x, lane = t&63, wv = t>>6;
  const int wr = wv>>1, wc = wv&1;
  const int cl = lane&15, g = lane>>4;

  f32x4 acc[4][4];
  const f32x4 z4 = {0.f,0.f,0.f,0.f};
  #pragma unroll
  for (int m=0;m<4;m++)
    #pragma unroll
    for (int n=0;n<4;n++) acc[m][n] = z4;

  const unsigned short* ab_h = mhi + (size_t)b*HID*HID;
  const unsigned short* bb_h = qhp + ((size_t)b*NSP + n0)*HID;
  const int rowc = lane >> 3;
  const int gcol = 8*((lane & 7) ^ rowc);

  for (int kt=0; kt<4; kt++){
    const int k0 = kt*64;
    __syncthreads();
    #pragma unroll
    for (int j=0;j<4;j++){
      const int rg = wv*4 + j;
      const int rr = rg*8 + rowc;
      gl16(&ab_h[(size_t)(o0+rr)*HID + k0 + gcol], &Ah[rg*512]);
      gl16(&bb_h[(size_t)rr*HID      + k0 + gcol], &Bh[rg*512]);
    }
    __syncthreads();
    #pragma unroll
    for (int kk=0;kk<2;kk++){
      const int ko = kk*32 + g*8;
      const int kosw = ko ^ ((cl & 7) << 3);
      bf16x8 ah[4], bh[4];
      #pragma unroll
      for (int m=0;m<4;m++)
        ah[m] = ldb8(&Ah[(wr*64 + m*16 + cl)*64 + kosw]);
      #pragma unroll
      for (int n=0;n<4;n++)
        bh[n] = ldb8(&Bh[(wc*64 + n*16 + cl)*64 + kosw]);
      #pragma unroll
      for (int m=0;m<4;m++)
        #pragma unroll
        for (int n=0;n<4;n++)
          acc[m][n] = mfma16(ah[m], bh[n], acc[m][n]);
    }
  }

  // LN coefficients: out = acc*ga + (beta + (bout-mean)*ga)
  const float inv = 1.f/1048576.f;
  const float mean = bsum[b]*inv;
  const float var  = bssq[b]*inv - mean*mean;
  const float ri = rsqrtf(var + 1e-5f);
  float gav[4][4], bev[4][4];
  #pragma unroll
  for (int m=0;m<4;m++)
    #pragma unroll
    for (int i=0;i<4;i++){
      const int o = o0 + wr*64 + m*16 + g*4 + i;
      const float ga = gamma[o]*ri;
      gav[m][i] = ga;
      bev[m][i] = beta[o] + (bout[o]-mean)*ga;
    }

  #pragma unroll
  for (int p=0;p<2;p++){
    __syncthreads();
    #pragma unroll
    for (int mm=0;mm<2;mm++){
      const int m = 2*p+mm;
      #pragma unroll
      for (int nf=0;nf<4;nf++)
        #pragma unroll
        for (int i=0;i<4;i++){
          const int lr = wr*32 + mm*16 + g*4 + i;
          const int col = wc*64 + nf*16 + cl;
          stg[lr*128 + (col ^ ((lr&7)<<2))] = acc[m][nf][i]*gav[m][i] + bev[m][i];
        }
    }
    __syncthreads();
    #pragma unroll
    for (int i2=0;i2<8;i2++){
      const int lr = wv*16 + i2*2 + (lane>>5);
      const int colw = (lane&31)*4;
      f32x4 v = *(const f32x4*)&stg[lr*128 + (colw ^ ((lr&7)<<2))];
      const int dg = o0 + (lr>>5)*64 + p*32 + (lr&31);
      *(f32x4*)&out[((size_t)b*HID + dg)*NSP + n0 + colw] = v;
    }
  }
}

// ---------------- workspace layout (bytes) ----------------
#define OFF_XT     0ull           // ushort [16][4096][256]  32MB
#define OFF_QH     33554432ull    // ushort [16][4096][256]  32MB
#define OFF_CTXP   67108864ull    // float [16][8][8][1024]  4MB
#define OFF_MH     71303168ull    // ushort [16][256][256]   2MB
#define OFF_LK     73400320ull    // float [16][256]
#define OFF_LQ     73416704ull
#define OFF_WHI    73433088ull    // ushort [768][256]
#define OFF_KSUM   73826304ull    // float [16][256]
#define OFF_BSUM   73842688ull    // float [16]
#define OFF_BSSQ   73842752ull    // float [16]

extern "C" void kernel_launch(void* const* d_in, const int* in_sizes, int n_in,
                              void* d_out, int out_size, void* d_ws, size_t ws_size,
                              hipStream_t stream) {
  const float* x     = (const float*)d_in[0];
  const float* cond  = (const float*)d_in[1];
  const float* wqkv  = (const float*)d_in[2];
  const float* wlk   = (const float*)d_in[3];
  const float* blk   = (const float*)d_in[4];
  const float* wlq   = (const float*)d_in[5];
  const float* blq   = (const float*)d_in[6];
  const float* wout  = (const float*)d_in[7];
  const float* bout  = (const float*)d_in[8];
  const float* gamma = (const float*)d_in[9];
  const float* beta  = (const float*)d_in[10];

  char* ws = (char*)d_ws;
  unsigned short* xt   = (unsigned short*)(ws + OFF_XT);
  unsigned short* qh   = (unsigned short*)(ws + OFF_QH);
  float*          ctxp = (float*)(ws + OFF_CTXP);
  unsigned short* mhi  = (unsigned short*)(ws + OFF_MH);
  float*          lk   = (float*)(ws + OFF_LK);
  float*          lq   = (float*)(ws + OFF_LQ);
  unsigned short* whi  = (unsigned short*)(ws + OFF_WHI);
  float*          ksum = (float*)(ws + OFF_KSUM);
  float*          bsum = (float*)(ws + OFF_BSUM);
  float*          bssq = (float*)(ws + OFF_BSSQ);

  // d_out doubles as scratch for fp8 kexp/v (consumed by k3 before k5b writes y)
  unsigned char* kexp = (unsigned char*)d_out;                // 16MB
  unsigned char* vscr = (unsigned char*)d_out + 16777216;     // 16MB
  float*         y    = (float*)d_out;

  hipMemsetAsync(ws + OFF_KSUM, 0, 16384 + 128, stream);

  k01_prep <<<dim3(5,64,16), 256, 0, stream>>>(x, xt, wqkv, cond, wlk, blk, wlq, blq, whi, lk, lq);
  k2_gemm1 <<<dim3(32,3,16), 512, 0, stream>>>(whi, xt, lk, lq, qh, kexp, vscr, ksum);
  k3_ctx   <<<dim3(2,8,16), 256, 0, stream>>>(kexp, vscr, ctxp);
  k4_m     <<<dim3(8,16), 256, 0, stream>>>(ctxp, ksum, wout, mhi);
  k5a_stats<<<dim3(32,2,16), 256, 0, stream>>>(mhi, qh, bout, bsum, bssq);
  k5b_write<<<dim3(32,2,16), 256, 0, stream>>>(mhi, qh, bout, bsum, bssq, gamma, beta, y);
}